// Round 2
// baseline (426.238 us; speedup 1.0000x reference)
//
#include <hip/hip_runtime.h>
#include <hip/hip_bf16.h>

#define NB 8192        // batch rows
#define M1T 139264     // NB * 17 rows in layer-1

typedef __attribute__((ext_vector_type(8))) short bf16x8;
typedef __attribute__((ext_vector_type(16))) float f32x16;

__device__ __forceinline__ unsigned short f2b(float f) {
  union { float f; unsigned u; } v; v.f = f;
  unsigned r = v.u + 0x7fffu + ((v.u >> 16) & 1u);   // RNE
  return (unsigned short)(r >> 16);
}
__device__ __forceinline__ float b2f(unsigned u16) {
  union { unsigned u; float f; } v; v.u = u16 << 16;
  return v.f;
}
__device__ __forceinline__ bf16x8 pack8(float a0, float a1, float a2, float a3,
                                        float a4, float a5, float a6, float a7) {
  bf16x8 r;
  r[0] = (short)f2b(a0); r[1] = (short)f2b(a1); r[2] = (short)f2b(a2); r[3] = (short)f2b(a3);
  r[4] = (short)f2b(a4); r[5] = (short)f2b(a5); r[6] = (short)f2b(a6); r[7] = (short)f2b(a7);
  return r;
}

#define GLDS16(g, l)                                                          \
  __builtin_amdgcn_global_load_lds(                                           \
      (const __attribute__((address_space(1))) unsigned int*)(const void*)(g),\
      (__attribute__((address_space(3))) unsigned int*)(void*)(l), 16, 0, 0)

// ---- kernel 0: W1/W2 fp32 -> bf16, PRE-SWIZZLED per-kt tile layout ----
// out elem offset = kt*16384 + n*64 + sw*8 + e, sw = slot ^ (n&7)
__global__ void convert_w(const float* __restrict__ W1, const float* __restrict__ W2,
                          unsigned short* __restrict__ W1s, unsigned short* __restrict__ W2s) {
  int i = blockIdx.x * 256 + threadIdx.x;  // 0..65535, one float4 each
  const float* W; unsigned short* out; int f4;
  if (i < 32768) { W = W1; out = W1s; f4 = i; }
  else           { W = W2; out = W2s; f4 = i - 32768; }
  int n  = (f4 * 4) >> 9;        // row 0..255
  int c0 = (f4 * 4) & 511;       // col of first elem
  int kt = c0 >> 6;
  int slot = (c0 & 63) >> 3;
  int e  = c0 & 7;               // 0 or 4
  int sw = slot ^ (n & 7);
  float4 v = *((const float4*)W + f4);
  ushort4 o;
  o.x = f2b(v.x); o.y = f2b(v.y); o.z = f2b(v.z); o.w = f2b(v.w);
  *(ushort4*)(out + kt * 16384 + n * 64 + sw * 8 + e) = o;
}

// ---- layer 1: h1 = relu([self || mean4(neigh2)] @ W1^T), bf16 out ----
// BM=64, BN=256, 256 threads = 4 waves; wave w owns cols [w*64, w*64+64).
// A-fragments gathered DIRECTLY into registers (lane = row, lh = k-half).
// B double-buffered in LDS via global_load_lds (pre-swizzled source).
__global__ __launch_bounds__(256, 2)
void sage_l1(const float* __restrict__ feats,
             const unsigned short* __restrict__ Wbs,
             const int* __restrict__ batch_nodes,
             const int* __restrict__ neigh1,
             const int* __restrict__ neigh2,
             unsigned short* __restrict__ h1b)
{
  __shared__ __align__(16) unsigned short Bsm[2][256 * 64];   // 2 x 32 KB
  const int tid = threadIdx.x;
  const int m0 = blockIdx.x * 64;
  const int w = tid >> 6;
  const int l31 = tid & 31;
  const int lh = (tid & 63) >> 5;

  // per-lane row node ids + row pointers (lanes with same l31 duplicate: L1-hit)
  const int r0 = m0 + l31, r1 = m0 + 32 + l31;
  const int self0 = (r0 < NB) ? batch_nodes[r0] : neigh1[r0 - NB];
  const int self1 = (r1 < NB) ? batch_nodes[r1] : neigh1[r1 - NB];
  const int4 nb0 = *(const int4*)(neigh2 + (size_t)r0 * 4);
  const int4 nb1 = *(const int4*)(neigh2 + (size_t)r1 * 4);
  const float* sp[2]  = { feats + (size_t)self0 * 256, feats + (size_t)self1 * 256 };
  const float* ap0[4] = { feats + (size_t)nb0.x * 256, feats + (size_t)nb0.y * 256,
                          feats + (size_t)nb0.z * 256, feats + (size_t)nb0.w * 256 };
  const float* ap1[4] = { feats + (size_t)nb1.x * 256, feats + (size_t)nb1.y * 256,
                          feats + (size_t)nb1.z * 256, feats + (size_t)nb1.w * 256 };

  f32x16 acc[2][2] = {};

  // prologue: stage B(0)
  {
    const unsigned short* src = Wbs;           // kt = 0
    #pragma unroll
    for (int p = 0; p < 8; ++p) {
      int i = p * 256 + tid;
      GLDS16(src + (size_t)i * 8, &Bsm[0][i * 8]);
    }
  }
  __syncthreads();

  for (int kt = 0; kt < 8; ++kt) {
    // stage B(kt+1) into the other buffer (fire-and-forget, drained at barrier)
    if (kt < 7) {
      const unsigned short* src = Wbs + (size_t)(kt + 1) * 16384;
      unsigned short* dst = &Bsm[(kt + 1) & 1][0];
      #pragma unroll
      for (int p = 0; p < 8; ++p) {
        int i = p * 256 + tid;
        GLDS16(src + (size_t)i * 8, dst + i * 8);
      }
    }

    // ---- A fragments for this kt, straight into registers
    bf16x8 af[2][4];
    if (kt < 4) {                       // self half
      #pragma unroll
      for (int mi = 0; mi < 2; ++mi) {
        const float* p = sp[mi] + kt * 64 + lh * 8;
        #pragma unroll
        for (int kk = 0; kk < 4; ++kk) {
          float4 x = *(const float4*)(p + kk * 16);
          float4 y = *(const float4*)(p + kk * 16 + 4);
          af[mi][kk] = pack8(x.x, x.y, x.z, x.w, y.x, y.y, y.z, y.w);
        }
      }
    } else {                            // agg half: mean of 4 neighbor rows
      const int kb = (kt - 4) * 64 + lh * 8;
      #pragma unroll
      for (int kk = 0; kk < 4; ++kk) {
        #pragma unroll
        for (int mi = 0; mi < 2; ++mi) {
          float s0 = 0, s1 = 0, s2 = 0, s3 = 0, s4 = 0, s5 = 0, s6 = 0, s7 = 0;
          #pragma unroll
          for (int j = 0; j < 4; ++j) {
            const float* p = (mi ? ap1[j] : ap0[j]) + kb + kk * 16;
            float4 x = *(const float4*)(p);
            float4 y = *(const float4*)(p + 4);
            s0 += x.x; s1 += x.y; s2 += x.z; s3 += x.w;
            s4 += y.x; s5 += y.y; s6 += y.z; s7 += y.w;
          }
          af[mi][kk] = pack8(s0 * 0.25f, s1 * 0.25f, s2 * 0.25f, s3 * 0.25f,
                             s4 * 0.25f, s5 * 0.25f, s6 * 0.25f, s7 * 0.25f);
        }
      }
    }

    // ---- MFMA against LDS-resident B(kt)
    const unsigned short* Bc = &Bsm[kt & 1][0];
    const int n0 = w * 64 + l31, n1 = n0 + 32;
    #pragma unroll
    for (int kk = 0; kk < 4; ++kk) {
      int sl = kk * 2 + lh;
      bf16x8 b0 = *(const bf16x8*)(Bc + n0 * 64 + ((sl ^ (n0 & 7)) << 3));
      bf16x8 b1 = *(const bf16x8*)(Bc + n1 * 64 + ((sl ^ (n1 & 7)) << 3));
      acc[0][0] = __builtin_amdgcn_mfma_f32_32x32x16_bf16(af[0][kk], b0, acc[0][0], 0, 0, 0);
      acc[0][1] = __builtin_amdgcn_mfma_f32_32x32x16_bf16(af[0][kk], b1, acc[0][1], 0, 0, 0);
      acc[1][0] = __builtin_amdgcn_mfma_f32_32x32x16_bf16(af[1][kk], b0, acc[1][0], 0, 0, 0);
      acc[1][1] = __builtin_amdgcn_mfma_f32_32x32x16_bf16(af[1][kk], b1, acc[1][1], 0, 0, 0);
    }
    __syncthreads();   // drains B(kt+1) glds; protects buffer reuse
  }

  // ---- epilogue: relu -> bf16 h1
  #pragma unroll
  for (int mi = 0; mi < 2; ++mi)
    #pragma unroll
    for (int ni = 0; ni < 2; ++ni)
      #pragma unroll
      for (int q = 0; q < 16; ++q) {
        int row = m0 + mi * 32 + (q & 3) + 8 * (q >> 2) + 4 * lh;
        int col = w * 64 + ni * 32 + l31;
        float v = acc[mi][ni][q];
        v = v > 0.f ? v : 0.f;
        h1b[(size_t)row * 256 + col] = f2b(v);
      }
}

// ---- layer 2: out = relu([h1_self || mean16(h1_neigh)] @ W2^T), fp32 out ----
// BM=32 -> 256 blocks (one per CU). Wave tile 32x64. A-direct from bf16 h1.
__global__ __launch_bounds__(256, 2)
void sage_l2(const unsigned short* __restrict__ h1b,
             const unsigned short* __restrict__ Wbs,
             float* __restrict__ out)
{
  __shared__ __align__(16) unsigned short Bsm[2][256 * 64];
  const int tid = threadIdx.x;
  const int m0 = blockIdx.x * 32;
  const int w = tid >> 6;
  const int l31 = tid & 31;
  const int lh = (tid & 63) >> 5;

  const int r = m0 + l31;
  const unsigned short* selfp = h1b + (size_t)r * 256;
  const unsigned short* aggp  = h1b + (size_t)(NB + r * 16) * 256;

  f32x16 acc[2] = {};

  {
    #pragma unroll
    for (int p = 0; p < 8; ++p) {
      int i = p * 256 + tid;
      GLDS16(Wbs + (size_t)i * 8, &Bsm[0][i * 8]);
    }
  }
  __syncthreads();

  for (int kt = 0; kt < 8; ++kt) {
    if (kt < 7) {
      const unsigned short* src = Wbs + (size_t)(kt + 1) * 16384;
      unsigned short* dst = &Bsm[(kt + 1) & 1][0];
      #pragma unroll
      for (int p = 0; p < 8; ++p) {
        int i = p * 256 + tid;
        GLDS16(src + (size_t)i * 8, dst + i * 8);
      }
    }

    bf16x8 af[4];
    if (kt < 4) {                       // self half: already bf16, direct frags
      #pragma unroll
      for (int kk = 0; kk < 4; ++kk)
        af[kk] = *(const bf16x8*)(selfp + kt * 64 + kk * 16 + lh * 8);
    } else {                            // agg half: mean of 16 contiguous h1 rows
      const int kb = (kt - 4) * 64 + lh * 8;
      #pragma unroll
      for (int kk = 0; kk < 4; ++kk) {
        float s0 = 0, s1 = 0, s2 = 0, s3 = 0, s4 = 0, s5 = 0, s6 = 0, s7 = 0;
        #pragma unroll
        for (int j = 0; j < 16; ++j) {
          bf16x8 v = *(const bf16x8*)(aggp + (size_t)j * 256 + kb + kk * 16);
          s0 += b2f((unsigned short)v[0]); s1 += b2f((unsigned short)v[1]);
          s2 += b2f((unsigned short)v[2]); s3 += b2f((unsigned short)v[3]);
          s4 += b2f((unsigned short)v[4]); s5 += b2f((unsigned short)v[5]);
          s6 += b2f((unsigned short)v[6]); s7 += b2f((unsigned short)v[7]);
        }
        const float q = 1.0f / 16.0f;
        af[kk] = pack8(s0 * q, s1 * q, s2 * q, s3 * q, s4 * q, s5 * q, s6 * q, s7 * q);
      }
    }

    const unsigned short* Bc = &Bsm[kt & 1][0];
    const int n0 = w * 64 + l31, n1 = n0 + 32;
    #pragma unroll
    for (int kk = 0; kk < 4; ++kk) {
      int sl = kk * 2 + lh;
      bf16x8 b0 = *(const bf16x8*)(Bc + n0 * 64 + ((sl ^ (n0 & 7)) << 3));
      bf16x8 b1 = *(const bf16x8*)(Bc + n1 * 64 + ((sl ^ (n1 & 7)) << 3));
      acc[0] = __builtin_amdgcn_mfma_f32_32x32x16_bf16(af[kk], b0, acc[0], 0, 0, 0);
      acc[1] = __builtin_amdgcn_mfma_f32_32x32x16_bf16(af[kk], b1, acc[1], 0, 0, 0);
    }
    __syncthreads();
  }

  #pragma unroll
  for (int ni = 0; ni < 2; ++ni)
    #pragma unroll
    for (int q = 0; q < 16; ++q) {
      int row = m0 + (q & 3) + 8 * (q >> 2) + 4 * lh;
      int col = w * 64 + ni * 32 + l31;
      float v = acc[ni][q];
      out[(size_t)row * 256 + col] = v > 0.f ? v : 0.f;
    }
}

extern "C" void kernel_launch(void* const* d_in, const int* in_sizes, int n_in,
                              void* d_out, int out_size, void* d_ws, size_t ws_size,
                              hipStream_t stream) {
  const float* feats       = (const float*)d_in[0];
  const float* W1          = (const float*)d_in[1];
  const float* W2          = (const float*)d_in[2];
  const int*   batch_nodes = (const int*)d_in[3];
  const int*   neigh1      = (const int*)d_in[4];
  const int*   neigh2      = (const int*)d_in[5];
  float* out = (float*)d_out;

  unsigned short* W1s = (unsigned short*)d_ws;            // 131072 elems (swizzled)
  unsigned short* W2s = W1s + 131072;                     // 131072 elems (swizzled)
  unsigned short* h1b = W2s + 131072;                     // 139264*256 elems (~71 MB)

  hipLaunchKernelGGL(convert_w, dim3(256), dim3(256), 0, stream, W1, W2, W1s, W2s);
  hipLaunchKernelGGL(sage_l1, dim3(M1T / 64), dim3(256), 0, stream,
                     feats, W1s, batch_nodes, neigh1, neigh2, h1b);
  hipLaunchKernelGGL(sage_l2, dim3(NB / 32), dim3(256), 0, stream, h1b, W2s, out);
}

// Round 3
// 153.623 us; speedup vs baseline: 2.7746x; 2.7746x over previous
//
#include <hip/hip_runtime.h>
#include <hip/hip_bf16.h>

#define NB 8192        // batch rows
#define M1T 139264     // NB * 17 rows in layer-1

typedef __attribute__((ext_vector_type(8))) short bf16x8;
typedef __attribute__((ext_vector_type(16))) float f32x16;

__device__ __forceinline__ unsigned short f2b(float f) {
  union { float f; unsigned u; } v; v.f = f;
  unsigned r = v.u + 0x7fffu + ((v.u >> 16) & 1u);   // RNE
  return (unsigned short)(r >> 16);
}
__device__ __forceinline__ float b2f(unsigned u16) {
  union { unsigned u; float f; } v; v.u = u16 << 16;
  return v.f;
}
__device__ __forceinline__ uint4 pack8u(float a0, float a1, float a2, float a3,
                                        float a4, float a5, float a6, float a7) {
  uint4 v;
  v.x = (unsigned)f2b(a0) | ((unsigned)f2b(a1) << 16);
  v.y = (unsigned)f2b(a2) | ((unsigned)f2b(a3) << 16);
  v.z = (unsigned)f2b(a4) | ((unsigned)f2b(a5) << 16);
  v.w = (unsigned)f2b(a6) | ((unsigned)f2b(a7) << 16);
  return v;
}

#define GLDS16(g, l)                                                          \
  __builtin_amdgcn_global_load_lds(                                           \
      (const __attribute__((address_space(1))) unsigned int*)(const void*)(g),\
      (__attribute__((address_space(3))) unsigned int*)(void*)(l), 16, 0, 0)

// counted barrier: drain LDS ops only, leave global loads/glds in flight
#define BAR_LGKM()                                                            \
  do { asm volatile("s_waitcnt lgkmcnt(0)" ::: "memory");                     \
       __builtin_amdgcn_s_barrier(); } while (0)

// ---- kernel 0: W1/W2 fp32 -> bf16, PRE-SWIZZLED per-kt tile layout ----
// out elem offset = kt*16384 + n*64 + (slot^(n&7))*8 + e
__global__ void convert_w(const float* __restrict__ W1, const float* __restrict__ W2,
                          unsigned short* __restrict__ W1s, unsigned short* __restrict__ W2s) {
  int i = blockIdx.x * 256 + threadIdx.x;  // 0..65535, one float4 each
  const float* W; unsigned short* out; int f4;
  if (i < 32768) { W = W1; out = W1s; f4 = i; }
  else           { W = W2; out = W2s; f4 = i - 32768; }
  int n  = (f4 * 4) >> 9;
  int c0 = (f4 * 4) & 511;
  int kt = c0 >> 6;
  int slot = (c0 & 63) >> 3;
  int e  = c0 & 7;               // 0 or 4
  int sw = slot ^ (n & 7);
  float4 v = *((const float4*)W + f4);
  ushort4 o;
  o.x = f2b(v.x); o.y = f2b(v.y); o.z = f2b(v.z); o.w = f2b(v.w);
  *(ushort4*)(out + kt * 16384 + n * 64 + sw * 8 + e) = o;
}

// ---- layer 1: h1 = relu([self || mean4(neigh2)] @ W1^T), bf16 out ----
// BM=64, BN=256, 512 threads = 8 waves. Wave w: rows (w&1)*32, cols (w>>1)*64.
// Cooperative A staging (1 slot of 8 elems / thread), loads prefetched one kt
// ahead into registers; B via global_load_lds double-buffered one kt ahead.
__global__ __launch_bounds__(512, 4)
void sage_l1(const float* __restrict__ feats,
             const unsigned short* __restrict__ Wbs,
             const int* __restrict__ batch_nodes,
             const int* __restrict__ neigh1,
             const int* __restrict__ neigh2,
             unsigned short* __restrict__ h1b)
{
  __shared__ __align__(16) unsigned short As[2][64 * 64];    // 2 x 8 KB
  __shared__ __align__(16) unsigned short Bs[2][256 * 64];   // 2 x 32 KB
  const int tid = threadIdx.x;
  const int m0 = blockIdx.x * 64;
  const int w = tid >> 6, lane = tid & 63, l31 = lane & 31, lh = lane >> 5;
  const int mh = w & 1, nq = w >> 1;
  const int m = tid >> 3, slot = tid & 7;
  const int r = m0 + m;

  const int self = (r < NB) ? batch_nodes[r] : neigh1[r - NB];
  const int4 nb = *(const int4*)(neigh2 + (size_t)r * 4);
  const float* sp = feats + (size_t)self * 256;
  const float* ap[4] = { feats + (size_t)nb.x * 256, feats + (size_t)nb.y * 256,
                         feats + (size_t)nb.z * 256, feats + (size_t)nb.w * 256 };

  f32x16 acc[2] = {};
  float4 araw[8];

  #define ISSUE_B1(kt, buf)                                                   \
    do { const unsigned short* _s = Wbs + (size_t)(kt) * 16384;               \
         unsigned short* _d = &Bs[buf][0];                                    \
         _Pragma("unroll")                                                    \
         for (int q = 0; q < 4; ++q) {                                        \
           int i = q * 512 + tid;                                             \
           GLDS16(_s + (size_t)i * 8, _d + i * 8);                            \
         } } while (0)

  #define ISSUE_A1(kt)                                                        \
    do { if ((kt) < 4) {                                                      \
           const float* _p = sp + (kt) * 64 + slot * 8;                       \
           araw[0] = *(const float4*)_p; araw[1] = *(const float4*)(_p + 4);  \
         } else {                                                             \
           const int _kb = ((kt) - 4) * 64 + slot * 8;                        \
           _Pragma("unroll")                                                  \
           for (int j = 0; j < 4; ++j) {                                      \
             const float* _p = ap[j] + _kb;                                   \
             araw[2*j]   = *(const float4*)_p;                                \
             araw[2*j+1] = *(const float4*)(_p + 4);                          \
           } } } while (0)

  // prologue: kt=0 in flight
  ISSUE_B1(0, 0);
  ISSUE_A1(0);

  #pragma unroll
  for (int kt = 0; kt < 8; ++kt) {
    const int cur = kt & 1;
    // convert A(kt) (compiler waits the register loads; drains B(kt) glds too)
    uint4 av;
    if (kt < 4) {
      av = pack8u(araw[0].x, araw[0].y, araw[0].z, araw[0].w,
                  araw[1].x, araw[1].y, araw[1].z, araw[1].w);
    } else {
      float s0 = araw[0].x + araw[2].x + araw[4].x + araw[6].x;
      float s1 = araw[0].y + araw[2].y + araw[4].y + araw[6].y;
      float s2 = araw[0].z + araw[2].z + araw[4].z + araw[6].z;
      float s3 = araw[0].w + araw[2].w + araw[4].w + araw[6].w;
      float s4 = araw[1].x + araw[3].x + araw[5].x + araw[7].x;
      float s5 = araw[1].y + araw[3].y + araw[5].y + araw[7].y;
      float s6 = araw[1].z + araw[3].z + araw[5].z + araw[7].z;
      float s7 = araw[1].w + araw[3].w + araw[5].w + araw[7].w;
      av = pack8u(s0 * 0.25f, s1 * 0.25f, s2 * 0.25f, s3 * 0.25f,
                  s4 * 0.25f, s5 * 0.25f, s6 * 0.25f, s7 * 0.25f);
    }
    __syncthreads();                       // #1 — vmcnt/lgkm already ~0: free
    *(uint4*)(&As[cur][m * 64 + ((slot ^ (m & 7)) << 3)]) = av;
    if (kt < 7) { ISSUE_B1(kt + 1, cur ^ 1); ISSUE_A1(kt + 1); }
    BAR_LGKM();                            // #2 — keeps kt+1 loads in flight
    // MFMA over As[cur], Bs[cur]
    {
      const int arow = mh * 32 + l31;
      const int n0 = nq * 64 + l31, n1 = n0 + 32;
      __builtin_amdgcn_s_setprio(1);
      #pragma unroll
      for (int kk = 0; kk < 4; ++kk) {
        int sl = kk * 2 + lh;
        bf16x8 a  = *(const bf16x8*)(&As[cur][arow * 64 + ((sl ^ (arow & 7)) << 3)]);
        bf16x8 b0 = *(const bf16x8*)(&Bs[cur][n0 * 64 + ((sl ^ (n0 & 7)) << 3)]);
        bf16x8 b1 = *(const bf16x8*)(&Bs[cur][n1 * 64 + ((sl ^ (n1 & 7)) << 3)]);
        acc[0] = __builtin_amdgcn_mfma_f32_32x32x16_bf16(a, b0, acc[0], 0, 0, 0);
        acc[1] = __builtin_amdgcn_mfma_f32_32x32x16_bf16(a, b1, acc[1], 0, 0, 0);
      }
      __builtin_amdgcn_s_setprio(0);
    }
  }
  #undef ISSUE_B1
  #undef ISSUE_A1

  // epilogue: relu -> bf16 h1
  #pragma unroll
  for (int ni = 0; ni < 2; ++ni)
    #pragma unroll
    for (int q = 0; q < 16; ++q) {
      int row = m0 + mh * 32 + (q & 3) + 8 * (q >> 2) + 4 * lh;
      int col = nq * 64 + ni * 32 + l31;
      float v = acc[ni][q];
      v = v > 0.f ? v : 0.f;
      h1b[(size_t)row * 256 + col] = f2b(v);
    }
}

// ---- layer 2: out = relu([h1_self || mean16(h1_neigh)] @ W2^T), fp32 out ----
// BM=32 -> 256 blocks, 256 threads = 4 waves; wave w: all 32 rows, cols w*64.
__global__ __launch_bounds__(256, 2)
void sage_l2(const unsigned short* __restrict__ h1b,
             const unsigned short* __restrict__ Wbs,
             float* __restrict__ out)
{
  __shared__ __align__(16) unsigned short As[2][32 * 64];    // 2 x 4 KB
  __shared__ __align__(16) unsigned short Bs[2][256 * 64];   // 2 x 32 KB
  const int tid = threadIdx.x;
  const int m0 = blockIdx.x * 32;
  const int w = tid >> 6, lane = tid & 63, l31 = lane & 31, lh = lane >> 5;
  const int m = tid >> 3, slot = tid & 7;
  const int r = m0 + m;

  const unsigned short* selfp = h1b + (size_t)r * 256;
  const unsigned short* aggp  = h1b + (size_t)(NB + r * 16) * 256;

  f32x16 acc[2] = {};
  uint4 braw[16];

  #define ISSUE_B2(kt, buf)                                                   \
    do { const unsigned short* _s = Wbs + (size_t)(kt) * 16384;               \
         unsigned short* _d = &Bs[buf][0];                                    \
         _Pragma("unroll")                                                    \
         for (int q = 0; q < 8; ++q) {                                        \
           int i = q * 256 + tid;                                             \
           GLDS16(_s + (size_t)i * 8, _d + i * 8);                            \
         } } while (0)

  #define ISSUE_A2(kt)                                                        \
    do { if ((kt) < 4) {                                                      \
           braw[0] = *(const uint4*)(selfp + (kt) * 64 + slot * 8);           \
         } else {                                                             \
           const int _kb = ((kt) - 4) * 64 + slot * 8;                        \
           _Pragma("unroll")                                                  \
           for (int j = 0; j < 16; ++j)                                       \
             braw[j] = *(const uint4*)(aggp + (size_t)j * 256 + _kb);         \
         } } while (0)

  ISSUE_B2(0, 0);
  ISSUE_A2(0);

  #pragma unroll
  for (int kt = 0; kt < 8; ++kt) {
    const int cur = kt & 1;
    uint4 av;
    if (kt < 4) {
      av = braw[0];                        // already bf16 in layout
    } else {
      float s0 = 0, s1 = 0, s2 = 0, s3 = 0, s4 = 0, s5 = 0, s6 = 0, s7 = 0;
      #pragma unroll
      for (int j = 0; j < 16; ++j) {
        s0 += b2f(braw[j].x & 0xffffu); s1 += b2f(braw[j].x >> 16);
        s2 += b2f(braw[j].y & 0xffffu); s3 += b2f(braw[j].y >> 16);
        s4 += b2f(braw[j].z & 0xffffu); s5 += b2f(braw[j].z >> 16);
      s6 += b2f(braw[j].w & 0xffffu); s7 += b2f(braw[j].w >> 16);
      }
      const float q = 1.0f / 16.0f;
      av = pack8u(s0 * q, s1 * q, s2 * q, s3 * q, s4 * q, s5 * q, s6 * q, s7 * q);
    }
    __syncthreads();
    *(uint4*)(&As[cur][m * 64 + ((slot ^ (m & 7)) << 3)]) = av;
    if (kt < 7) { ISSUE_B2(kt + 1, cur ^ 1); ISSUE_A2(kt + 1); }
    BAR_LGKM();
    {
      const int arow = l31;
      const int n0 = w * 64 + l31, n1 = n0 + 32;
      __builtin_amdgcn_s_setprio(1);
      #pragma unroll
      for (int kk = 0; kk < 4; ++kk) {
        int sl = kk * 2 + lh;
        bf16x8 a  = *(const bf16x8*)(&As[cur][arow * 64 + ((sl ^ (arow & 7)) << 3)]);
        bf16x8 b0 = *(const bf16x8*)(&Bs[cur][n0 * 64 + ((sl ^ (n0 & 7)) << 3)]);
        bf16x8 b1 = *(const bf16x8*)(&Bs[cur][n1 * 64 + ((sl ^ (n1 & 7)) << 3)]);
        acc[0] = __builtin_amdgcn_mfma_f32_32x32x16_bf16(a, b0, acc[0], 0, 0, 0);
        acc[1] = __builtin_amdgcn_mfma_f32_32x32x16_bf16(a, b1, acc[1], 0, 0, 0);
      }
      __builtin_amdgcn_s_setprio(0);
    }
  }
  #undef ISSUE_B2
  #undef ISSUE_A2

  #pragma unroll
  for (int ni = 0; ni < 2; ++ni)
    #pragma unroll
    for (int q = 0; q < 16; ++q) {
      int row = m0 + (q & 3) + 8 * (q >> 2) + 4 * lh;
      int col = w * 64 + ni * 32 + l31;
      float v = acc[ni][q];
      out[(size_t)row * 256 + col] = v > 0.f ? v : 0.f;
    }
}

extern "C" void kernel_launch(void* const* d_in, const int* in_sizes, int n_in,
                              void* d_out, int out_size, void* d_ws, size_t ws_size,
                              hipStream_t stream) {
  const float* feats       = (const float*)d_in[0];
  const float* W1          = (const float*)d_in[1];
  const float* W2          = (const float*)d_in[2];
  const int*   batch_nodes = (const int*)d_in[3];
  const int*   neigh1      = (const int*)d_in[4];
  const int*   neigh2      = (const int*)d_in[5];
  float* out = (float*)d_out;

  unsigned short* W1s = (unsigned short*)d_ws;            // 131072 elems (swizzled)
  unsigned short* W2s = W1s + 131072;                     // 131072 elems (swizzled)
  unsigned short* h1b = W2s + 131072;                     // 139264*256 elems (~71 MB)

  hipLaunchKernelGGL(convert_w, dim3(256), dim3(256), 0, stream, W1, W2, W1s, W2s);
  hipLaunchKernelGGL(sage_l1, dim3(M1T / 64), dim3(512), 0, stream,
                     feats, W1s, batch_nodes, neigh1, neigh2, h1b);
  hipLaunchKernelGGL(sage_l2, dim3(NB / 32), dim3(256), 0, stream, h1b, W2s, out);
}